// Round 3
// baseline (1229.290 us; speedup 1.0000x reference)
//
#include <hip/hip_runtime.h>
#include <math.h>

#define V 50257
#define E 1024
#define H 1024
#define L 512

// d_out offsets (floats): [log_probs V][h_new H][attn_weights L]
#define OUT_H  50257
#define OUT_AW 51281

// ws offsets (floats) — total usage 49184 B, within the 57 KB proven in round 0
#define WS_S    0       // 512 attn scores
#define WS_X    1024    // 2048 x = [embedded, attn_applied]
#define WS_GH   3072    // 3072 gh
#define WS_GI   6144    // 3072 gi
#define WS_BM   10240   // 1024 per-block maxes
#define WS_BS   11264   // 1024 per-block sumexps
#define WS_BAR  12288   // 8 ints of barrier counters (byte offset 49152)

#define NB 1024         // grid: 4 blocks/CU x 256 CU, co-resident via launch_bounds(256,4)
#define NC 768          // compute blocks (P1-P3); rest prefetch out_W into LLC

__device__ __forceinline__ float dot4(const float4 a, const float4 b) {
    return a.x * b.x + a.y * b.y + a.z * b.z + a.w * b.w;
}

__device__ __forceinline__ float wave_sum(float v) {
    for (int off = 32; off > 0; off >>= 1) v += __shfl_down(v, off, 64);
    return v;
}

// Software grid barrier (plain launch, graph-capture safe).
// Device-scope release add + acquire spin; bounded spin = fail-fast, never hang.
__device__ __forceinline__ void gbar(int* bar, int idx, int target) {
    __syncthreads();
    if (threadIdx.x == 0) {
        __threadfence();  // release: make our block's writes device-visible
        __hip_atomic_fetch_add(&bar[idx], 1, __ATOMIC_RELEASE, __HIP_MEMORY_SCOPE_AGENT);
        int guard = 0;
        while (__hip_atomic_load(&bar[idx], __ATOMIC_ACQUIRE, __HIP_MEMORY_SCOPE_AGENT) < target) {
            __builtin_amdgcn_s_sleep(2);
            if (++guard > (1 << 22)) break;   // safety valve: wrong answer beats a hung container
        }
    }
    __syncthreads();
    __threadfence();      // acquire side: invalidate caches before reading others' data
}

__global__ __launch_bounds__(256, 4)
void fused(const int* __restrict__ input,
           const float* __restrict__ hidden,
           const float* __restrict__ enc,
           const float* __restrict__ emb_table,
           const float* __restrict__ attn_W,
           const float* __restrict__ attn_b,
           const float* __restrict__ W_ih,
           const float* __restrict__ W_hh,
           const float* __restrict__ b_ih,
           const float* __restrict__ b_hh,
           const float* __restrict__ out_W,
           const float* __restrict__ out_b,
           float* __restrict__ out,
           float* __restrict__ ws) {
    __shared__ float w[512];        // P2 softmax weights
    __shared__ float hn[H];         // P4 h_new
    __shared__ float redm[4], reds[4];
    __shared__ float bmax, bsum, off_s;

    const int t = threadIdx.x;
    const int lane = t & 63;
    const int wid = t >> 6;
    const int bid = blockIdx.x;
    int* bar = (int*)(ws + WS_BAR);
    const float4* h4 = (const float4*)hidden;

    if (bid < NC) {
        // ================= compute role: P1 -> P2 -> P3 =================
        const float* embrow = emb_table + (size_t)input[0] * E;

        // ---- P1: attn scores (0..511) + gh (512..3583) + zero x[E:] + stage emb ----
        for (int gw = bid * 4 + wid; gw < 3616; gw += NC * 4) {
            if (gw < L) {
                const float4* emb4 = (const float4*)embrow;
                const float4* w4 = (const float4*)(attn_W + (size_t)gw * (E + H));
                float acc = 0.f;
#pragma unroll
                for (int k = 0; k < 8; ++k) {
                    int i = lane + 64 * k;
                    float4 a = (k < 4) ? emb4[i] : h4[i - E / 4];
                    acc += dot4(a, w4[i]);
                }
                acc = wave_sum(acc);
                if (lane == 0) ws[WS_S + gw] = acc + attn_b[gw];
            } else if (gw < L + 3 * H) {
                int k = gw - L;
                const float4* w4 = (const float4*)(W_hh + (size_t)k * H);
                float acc = 0.f;
#pragma unroll
                for (int ii = 0; ii < 4; ++ii) {
                    int i = lane + 64 * ii;
                    acc += dot4(h4[i], w4[i]);
                }
                acc = wave_sum(acc);
                if (lane == 0) ws[WS_GH + k] = acc + b_hh[k];
            } else if (gw < 3600) {          // zero attn_applied accumulator
                ws[WS_X + E + (gw - 3584) * 64 + lane] = 0.f;
            } else {                         // stage embedded into x[0:E]
                int i = (gw - 3600) * 64 + lane;
                ws[WS_X + i] = embrow[i];
            }
        }

        gbar(bar, 0, NC);

        // ---- P2: redundant softmax + attn_applied on blocks 0..127 (J4 x L32) ----
        if (bid < 128) {
            float v0 = ws[WS_S + t];
            float v1 = ws[WS_S + 256 + t];
            float m = fmaxf(v0, v1);
            for (int off = 32; off > 0; off >>= 1) m = fmaxf(m, __shfl_down(m, off, 64));
            if (lane == 0) redm[wid] = m;
            __syncthreads();
            if (t == 0) bmax = fmaxf(fmaxf(redm[0], redm[1]), fmaxf(redm[2], redm[3]));
            __syncthreads();
            float e0 = expf(v0 - bmax), e1 = expf(v1 - bmax);
            float s = wave_sum(e0 + e1);
            if (lane == 0) reds[wid] = s;
            __syncthreads();
            if (t == 0) bsum = reds[0] + reds[1] + reds[2] + reds[3];
            __syncthreads();
            float inv = 1.f / bsum;
            w[t] = e0 * inv;
            w[256 + t] = e1 * inv;
            if (bid == 0) {
                out[OUT_AW + t] = e0 * inv;
                out[OUT_AW + 256 + t] = e1 * inv;
            }
            __syncthreads();
            const int j = (bid & 3) * 256 + t;     // 4 j-chunks of 256
            const int l0 = (bid >> 2) * 16;        // 32 l-chunks of 16
            float acc = 0.f;
#pragma unroll
            for (int l = l0; l < l0 + 16; ++l)
                acc += w[l] * enc[(size_t)l * H + j];
            atomicAdd(&ws[WS_X + E + j], acc);
        }

        gbar(bar, 1, NC);

        // ---- P3: gi = x @ W_ih^T + b_ih (3072 rows = 3072 waves exactly) ----
        {
            const int gw = bid * 4 + wid;
            const float4* x4 = (const float4*)(ws + WS_X);
            const float4* w4 = (const float4*)(W_ih + (size_t)gw * (E + H));
            float acc = 0.f;
#pragma unroll
            for (int k = 0; k < 8; ++k) {
                int i = lane + 64 * k;
                acc += dot4(x4[i], w4[i]);
            }
            acc = wave_sum(acc);
            if (lane == 0) ws[WS_GI + gw] = acc + b_ih[gw];
        }

        gbar(bar, 2, NB);
    } else {
        // ================= prefetch role: warm out_W in Infinity Cache =================
        // Runs concurrently with P1-P3; adaptively stops once P2 is done (bar[1] full).
        const int pfw = (bid - NC) * 4 + wid;      // 0..1023
        float dummy = 0.f;
        for (int k = 0; k < 50; ++k) {
            int row = pfw + k * 1024;
            if (row >= V) break;
            const float4* w4 = (const float4*)(out_W + (size_t)row * H);
#pragma unroll
            for (int ii = 0; ii < 4; ++ii) {
                float4 r = w4[lane + 64 * ii];
                dummy += r.x + r.y + r.z + r.w;
            }
            if ((k & 3) == 3 &&
                __hip_atomic_load(&bar[1], __ATOMIC_RELAXED, __HIP_MEMORY_SCOPE_AGENT) >= NC)
                break;
        }
        asm volatile("" :: "v"(dummy));            // keep prefetch loads live (no DCE)
        gbar(bar, 2, NB);
    }

    // ================= P4: all blocks — h_new (redundant) + logits + (m,s) =================
#pragma unroll
    for (int c = 0; c < 4; ++c) {
        int k = t + 256 * c;
        float gir = ws[WS_GI + k],         ghr = ws[WS_GH + k];
        float giz = ws[WS_GI + H + k],     ghz = ws[WS_GH + H + k];
        float gin = ws[WS_GI + 2 * H + k], ghn = ws[WS_GH + 2 * H + k];
        float r = 1.f / (1.f + expf(-(gir + ghr)));
        float z = 1.f / (1.f + expf(-(giz + ghz)));
        float n = tanhf(gin + r * ghn);
        float v = (1.f - z) * n + z * hidden[k];
        hn[k] = v;
        if (bid == 0) out[OUT_H + k] = v;
    }
    __syncthreads();

    {
        const float4* hn4 = (const float4*)hn;
        const int gwave = bid * 4 + wid;           // 4096 waves over V rows
        float m = -INFINITY, s = 0.f;
        for (int row = gwave; row < V; row += NB * 4) {
            const float4* w4 = (const float4*)(out_W + (size_t)row * H);
            float acc = 0.f;
#pragma unroll
            for (int ii = 0; ii < 4; ++ii) {
                int i = lane + 64 * ii;
                acc += dot4(hn4[i], w4[i]);
            }
            acc = wave_sum(acc);
            if (lane == 0) {
                float lg = acc + out_b[row];
                out[row] = lg;
                if (lg > m) { s = s * expf(m - lg) + 1.f; m = lg; }
                else        { s += expf(lg - m); }
            }
        }
        if (lane == 0) { redm[wid] = m; reds[wid] = s; }
        __syncthreads();
        if (t == 0) {
            float M = fmaxf(fmaxf(redm[0], redm[1]), fmaxf(redm[2], redm[3]));
            float S = reds[0] * expf(redm[0] - M) + reds[1] * expf(redm[1] - M)
                    + reds[2] * expf(redm[2] - M) + reds[3] * expf(redm[3] - M);
            ws[WS_BM + bid] = M;
            ws[WS_BS + bid] = S;
        }
    }

    gbar(bar, 3, NB);

    // ================= P5: redundant combine of 1024 (m,s) pairs, subtract =================
    {
        float m = -INFINITY, s = 0.f;
#pragma unroll
        for (int c = 0; c < 4; ++c) {
            int b = t + 256 * c;                   // 1024 pairs
            float bm = ws[WS_BM + b], bs = ws[WS_BS + b];
            float M2 = fmaxf(m, bm);
            s = s * expf(m - M2) + bs * expf(bm - M2);
            m = M2;
        }
        for (int off = 32; off > 0; off >>= 1) {
            float mo = __shfl_down(m, off, 64);
            float so = __shfl_down(s, off, 64);
            float M2 = fmaxf(m, mo);
            s = s * expf(m - M2) + so * expf(mo - M2);
            m = M2;
        }
        if (lane == 0) { redm[wid] = m; reds[wid] = s; }
        __syncthreads();
        if (t == 0) {
            float M = redm[0], S = reds[0];
            for (int i = 1; i < 4; ++i) {
                float M2 = fmaxf(M, redm[i]);
                S = S * expf(M - M2) + reds[i] * expf(redm[i] - M2);
                M = M2;
            }
            off_s = M + logf(S);
        }
        __syncthreads();
        int i = bid * 256 + t;                     // NB*256 = 262144 >= V
        if (i < V) out[i] -= off_s;
    }
}

extern "C" void kernel_launch(void* const* d_in, const int* in_sizes, int n_in,
                              void* d_out, int out_size, void* d_ws, size_t ws_size,
                              hipStream_t stream) {
    const int*   input   = (const int*)d_in[0];
    const float* hidden  = (const float*)d_in[1];
    const float* enc     = (const float*)d_in[2];
    const float* emb     = (const float*)d_in[3];
    const float* attn_W  = (const float*)d_in[4];
    const float* attn_b  = (const float*)d_in[5];
    const float* W_ih    = (const float*)d_in[6];
    const float* W_hh    = (const float*)d_in[7];
    const float* b_ih    = (const float*)d_in[8];
    const float* b_hh    = (const float*)d_in[9];
    const float* out_W   = (const float*)d_in[10];
    const float* out_b   = (const float*)d_in[11];
    float* out = (float*)d_out;
    float* ws  = (float*)d_ws;

    // zero the 8 barrier counters (capture-safe; replays re-zero each iteration)
    hipMemsetAsync((char*)d_ws + WS_BAR * sizeof(float), 0, 8 * sizeof(int), stream);

    fused<<<NB, 256, 0, stream>>>(input, hidden, enc, emb, attn_W, attn_b,
                                  W_ih, W_hh, b_ih, b_hh, out_W, out_b, out, ws);
}

// Round 4
// 420.859 us; speedup vs baseline: 2.9209x; 2.9209x over previous
//
#include <hip/hip_runtime.h>
#include <math.h>

#define V 50257
#define E 1024
#define H 1024
#define L 512

// d_out offsets (floats): [log_probs V][h_new H][attn_weights L]
#define OUT_H  50257
#define OUT_AW 51281

// ws offsets (floats)
#define WS_S    0       // 512 attn scores
#define WS_X    1024    // 2048 x = [embedded, attn_applied]
#define WS_GH   3072    // 3072 gh
#define WS_GI   6144    // 3072 gi
#define WS_BM   10240   // 2048 per-block maxes
#define WS_BS   12288   // 2048 per-block sumexps

__device__ __forceinline__ float dot4(const float4 a, const float4 b) {
    return a.x * b.x + a.y * b.y + a.z * b.z + a.w * b.w;
}

__device__ __forceinline__ float wave_sum(float v) {
    for (int off = 32; off > 0; off >>= 1) v += __shfl_down(v, off, 64);
    return v;
}

// K1: attn scores (waves 0..511) + gh (512..3583) + zero x[E:] (3584..3599)
//     + stage emb into x[0:E] (3600..3615).  904 blocks x 256.
__global__ void k1_scores_gh(const int* __restrict__ input,
                             const float* __restrict__ hidden,
                             const float* __restrict__ emb_table,
                             const float* __restrict__ attn_W,
                             const float* __restrict__ attn_b,
                             const float* __restrict__ W_hh,
                             const float* __restrict__ b_hh,
                             float* __restrict__ ws) {
    const int t = threadIdx.x;
    const int lane = t & 63;
    const int gwave = blockIdx.x * 4 + (t >> 6);
    const float4* h4 = (const float4*)hidden;
    const float* embrow = emb_table + (size_t)input[0] * E;

    if (gwave < L) {
        const float4* emb4 = (const float4*)embrow;
        const float4* w4 = (const float4*)(attn_W + (size_t)gwave * (E + H));
        float acc = 0.f;
#pragma unroll
        for (int k = 0; k < 8; ++k) {
            int i = lane + 64 * k;
            float4 a = (k < 4) ? emb4[i] : h4[i - E / 4];
            acc += dot4(a, w4[i]);
        }
        acc = wave_sum(acc);
        if (lane == 0) ws[WS_S + gwave] = acc + attn_b[gwave];
    } else if (gwave < L + 3 * H) {
        int k = gwave - L;
        const float4* w4 = (const float4*)(W_hh + (size_t)k * H);
        float acc = 0.f;
#pragma unroll
        for (int ii = 0; ii < 4; ++ii) {
            int i = lane + 64 * ii;
            acc += dot4(h4[i], w4[i]);
        }
        acc = wave_sum(acc);
        if (lane == 0) ws[WS_GH + k] = acc + b_hh[k];
    } else if (gwave < 3600) {          // zero attn_applied accumulator
        ws[WS_X + E + (gwave - 3584) * 64 + lane] = 0.f;
    } else if (gwave < 3616) {          // stage embedded into x[0:E]
        int i = (gwave - 3600) * 64 + lane;
        ws[WS_X + i] = embrow[i];
    }
}

// K2: redundant per-block softmax over 512 scores, then attn_applied slice.
//     128 blocks x 256: jc = blk&3 (j-chunk of 256), lc = blk>>2 (l-chunk of 16).
__global__ void k2_softmax_applied(const float* __restrict__ enc,
                                   float* __restrict__ ws,
                                   float* __restrict__ out) {
    __shared__ float w[512];
    __shared__ float redm[4], reds[4];
    __shared__ float bmax, bsum;
    const int t = threadIdx.x;
    const int lane = t & 63, wid = t >> 6;

    float v0 = ws[WS_S + t];
    float v1 = ws[WS_S + 256 + t];
    float m = fmaxf(v0, v1);
    for (int off = 32; off > 0; off >>= 1) m = fmaxf(m, __shfl_down(m, off, 64));
    if (lane == 0) redm[wid] = m;
    __syncthreads();
    if (t == 0) bmax = fmaxf(fmaxf(redm[0], redm[1]), fmaxf(redm[2], redm[3]));
    __syncthreads();
    float e0 = expf(v0 - bmax), e1 = expf(v1 - bmax);
    float s = wave_sum(e0 + e1);
    if (lane == 0) reds[wid] = s;
    __syncthreads();
    if (t == 0) bsum = reds[0] + reds[1] + reds[2] + reds[3];
    __syncthreads();
    float inv = 1.f / bsum;
    w[t] = e0 * inv;
    w[256 + t] = e1 * inv;
    if (blockIdx.x == 0) {
        out[OUT_AW + t] = e0 * inv;
        out[OUT_AW + 256 + t] = e1 * inv;
    }
    __syncthreads();

    const int j = (blockIdx.x & 3) * 256 + t;      // 4 j-chunks of 256
    const int l0 = (blockIdx.x >> 2) * 16;         // 32 l-chunks of 16
    float acc = 0.f;
#pragma unroll
    for (int l = l0; l < l0 + 16; ++l)
        acc += w[l] * enc[(size_t)l * H + j];
    atomicAdd(&ws[WS_X + E + j], acc);
}

// K3: gi = x @ W_ih^T + b_ih; one wave per row, 768 blocks x 256.
__global__ void k3_gi(const float* __restrict__ W_ih, const float* __restrict__ b_ih,
                      float* __restrict__ ws) {
    const int lane = threadIdx.x & 63;
    const int gwave = blockIdx.x * 4 + (threadIdx.x >> 6);
    const float4* x4 = (const float4*)(ws + WS_X);
    const float4* w4 = (const float4*)(W_ih + (size_t)gwave * (E + H));
    float acc = 0.f;
#pragma unroll
    for (int k = 0; k < 8; ++k) {
        int i = lane + 64 * k;
        acc += dot4(x4[i], w4[i]);
    }
    acc = wave_sum(acc);
    if (lane == 0) ws[WS_GI + gwave] = acc + b_ih[gwave];
}

// K4: redundant h_new per block -> LDS, then logits + per-block online (max,sumexp).
//     2048 blocks x 256. Row-0 of out_W prefetched into regs before the h_new
//     preamble (load latency hides under expf/tanh); hn fragment hoisted to regs.
__global__ void k4_logits(const float* __restrict__ hidden,
                          const float* __restrict__ out_W,
                          const float* __restrict__ out_b,
                          float* __restrict__ ws,
                          float* __restrict__ out) {
    __shared__ float hn[H];
    __shared__ float wm[4], wsum[4];
    const int t = threadIdx.x;
    const int lane = t & 63, wid = t >> 6;
    const int gwave = blockIdx.x * 4 + wid;        // 8192 waves, all < V

    // issue row-0 loads first: independent of everything, latency hides under hn calc
    const float4* w4_0 = (const float4*)(out_W + (size_t)gwave * H);
    float4 pre0 = w4_0[lane];
    float4 pre1 = w4_0[lane + 64];
    float4 pre2 = w4_0[lane + 128];
    float4 pre3 = w4_0[lane + 192];

    // h_new computed redundantly (gi/gh/hidden are L2-hot, 28 KB)
#pragma unroll
    for (int c = 0; c < 4; ++c) {
        int k = t + 256 * c;
        float gir = ws[WS_GI + k],         ghr = ws[WS_GH + k];
        float giz = ws[WS_GI + H + k],     ghz = ws[WS_GH + H + k];
        float gin = ws[WS_GI + 2 * H + k], ghn = ws[WS_GH + 2 * H + k];
        float r = 1.f / (1.f + expf(-(gir + ghr)));
        float z = 1.f / (1.f + expf(-(giz + ghz)));
        float n = tanhf(gin + r * ghn);
        float v = (1.f - z) * n + z * hidden[k];
        hn[k] = v;
        if (blockIdx.x == 0) out[OUT_H + k] = v;
    }
    __syncthreads();

    // hoist this lane's hn fragment into registers (reused every row)
    const float4* hn4 = (const float4*)hn;
    float4 h0 = hn4[lane];
    float4 h1 = hn4[lane + 64];
    float4 h2 = hn4[lane + 128];
    float4 h3 = hn4[lane + 192];

    float m = -INFINITY, s = 0.f;

    // row 0 from prefetch registers
    {
        float acc = dot4(h0, pre0) + dot4(h1, pre1) + dot4(h2, pre2) + dot4(h3, pre3);
        acc = wave_sum(acc);
        if (lane == 0) {
            float lg = acc + out_b[gwave];
            out[gwave] = lg;
            m = lg; s = 1.f;
        }
    }
    // remaining rows
    for (int row = gwave + 8192; row < V; row += 8192) {
        const float4* w4 = (const float4*)(out_W + (size_t)row * H);
        float acc = dot4(h0, w4[lane])
                  + dot4(h1, w4[lane + 64])
                  + dot4(h2, w4[lane + 128])
                  + dot4(h3, w4[lane + 192]);
        acc = wave_sum(acc);
        if (lane == 0) {
            float lg = acc + out_b[row];
            out[row] = lg;
            if (lg > m) { s = s * expf(m - lg) + 1.f; m = lg; }
            else        { s += expf(lg - m); }
        }
    }
    if (lane == 0) { wm[wid] = m; wsum[wid] = s; }
    __syncthreads();
    if (t == 0) {
        float M = fmaxf(fmaxf(wm[0], wm[1]), fmaxf(wm[2], wm[3]));
        float S = wsum[0] * expf(wm[0] - M) + wsum[1] * expf(wm[1] - M)
                + wsum[2] * expf(wm[2] - M) + wsum[3] * expf(wm[3] - M);
        ws[WS_BM + blockIdx.x] = M;
        ws[WS_BS + blockIdx.x] = S;
    }
}

// K5: each block redundantly combines the 2048 (m,s) pairs (16 KB, L2-hot),
//     then subtracts the logsumexp offset from its 256 logits. 197 blocks.
__global__ void k5_logprobs(const float* __restrict__ ws, float* __restrict__ out) {
    __shared__ float redm[4], reds[4];
    __shared__ float off_s;
    const int t = threadIdx.x;
    const int lane = t & 63, wid = t >> 6;
    float m = -INFINITY, s = 0.f;
#pragma unroll
    for (int c = 0; c < 8; ++c) {
        int b = t + 256 * c;
        float bm = ws[WS_BM + b], bs = ws[WS_BS + b];
        float M2 = fmaxf(m, bm);
        s = s * expf(m - M2) + bs * expf(bm - M2);
        m = M2;
    }
    for (int off = 32; off > 0; off >>= 1) {
        float mo = __shfl_down(m, off, 64);
        float so = __shfl_down(s, off, 64);
        float M2 = fmaxf(m, mo);
        s = s * expf(m - M2) + so * expf(mo - M2);
        m = M2;
    }
    if (lane == 0) { redm[wid] = m; reds[wid] = s; }
    __syncthreads();
    if (t == 0) {
        float M = redm[0], S = reds[0];
        for (int i = 1; i < 4; ++i) {
            float M2 = fmaxf(M, redm[i]);
            S = S * expf(M - M2) + reds[i] * expf(redm[i] - M2);
            M = M2;
        }
        off_s = M + logf(S);
    }
    __syncthreads();
    int i = blockIdx.x * 256 + t;
    if (i < V) out[i] -= off_s;
}

extern "C" void kernel_launch(void* const* d_in, const int* in_sizes, int n_in,
                              void* d_out, int out_size, void* d_ws, size_t ws_size,
                              hipStream_t stream) {
    const int*   input   = (const int*)d_in[0];
    const float* hidden  = (const float*)d_in[1];
    const float* enc     = (const float*)d_in[2];
    const float* emb     = (const float*)d_in[3];
    const float* attn_W  = (const float*)d_in[4];
    const float* attn_b  = (const float*)d_in[5];
    const float* W_ih    = (const float*)d_in[6];
    const float* W_hh    = (const float*)d_in[7];
    const float* b_ih    = (const float*)d_in[8];
    const float* b_hh    = (const float*)d_in[9];
    const float* out_W   = (const float*)d_in[10];
    const float* out_b   = (const float*)d_in[11];
    float* out = (float*)d_out;
    float* ws  = (float*)d_ws;

    k1_scores_gh<<<904, 256, 0, stream>>>(input, hidden, emb, attn_W, attn_b, W_hh, b_hh, ws);
    k2_softmax_applied<<<128, 256, 0, stream>>>(enc, ws, out);
    k3_gi<<<768, 256, 0, stream>>>(W_ih, b_ih, ws);
    k4_logits<<<2048, 256, 0, stream>>>(hidden, out_W, out_b, ws, out);
    k5_logprobs<<<197, 256, 0, stream>>>(ws, out);
}